// Round 10
// baseline (7035.430 us; speedup 1.0000x reference)
//
#include <hip/hip_runtime.h>
#include <hip/hip_bf16.h>

// Problem: B=32, T=128, I=H=O=512, L=2, bidirectional GRU + FC head.
// ws layout (bytes):
//   proj (bf16): [2][128][32][1536]            = 12,582,912 elems * 2B = 25.17 MB
//   seq  (fp32): [2][128][32][512]             =  4,194,304 elems * 4B = 16.78 MB
//   slabs(fp32): [2l][2d][128jb][6144]         =  6,291,456 elems * 4B = 25.17 MB
// total 67.12 MB; sync slots live in __device__ globals (zeroed by repack each launch)
#define PROJ_ELEMS 12582912
#define SEQ_ELEMS  4194304
#define SLAB_PER_BLK 6144

typedef float f32x4 __attribute__((ext_vector_type(4)));

// Wave-granular dataflow slots: g_slots[layer*4096 + (w*2+d)*128 + jb] = epoch
// published by WAVE w of block (d,jb): value t+1 means h(t)[2w..2w+1][4jb..4jb+4)
// is LLC-visible. Wave w consumes only rows 2w,2w+1 -> its producers are exactly
// the 128 (jb', w) waves -> per-wave poll, per-wave publish, NO block barriers.
// All traffic RELAXED agent-scope (sc1). Monotonic, no reset; layers disjoint.
__device__ unsigned g_slots[8192];

// ---------------- proj GEMM: [8192 x 1536] = src @ [Wxh | Wxr] + bias -> bf16 ----------------
// grid (12, 64), block 256. 128x128 tile, 8x8 per-thread register tile.
__global__ __launch_bounds__(256)
void proj_kernel(const float* __restrict__ src,
                 const float* __restrict__ Wxh, const float* __restrict__ bxh,
                 const float* __restrict__ Wxr, const float* __restrict__ bxr,
                 __hip_bfloat16* __restrict__ proj, int layer)
{
    __shared__ float As[32][137];   // [k][row] transposed A tile
    __shared__ float Ws[32][132];   // [k][col]
    const int tid  = threadIdx.x;
    const int col0 = blockIdx.x * 128;
    const int row0 = blockIdx.y * 128;
    const int d    = row0 >> 12;              // rows 0..4095 = dir0, 4096..8191 = dir1
    const int ld   = layer * 2 + d;
    const int tx = tid & 15, ty = tid >> 4;

    const bool is_xr = (col0 >= 1024);
    const float* Wbase = is_xr ? (Wxr + (size_t)ld * 512 * 512 + (col0 - 1024))
                               : (Wxh + (size_t)ld * 512 * 1024 + col0);
    const int wstride = is_xr ? 512 : 1024;
    const float* bias = is_xr ? (bxr + ld * 512 + (col0 - 1024))
                              : (bxh + ld * 1024 + col0);

    float acc[8][8];
    #pragma unroll
    for (int i = 0; i < 8; i++)
        #pragma unroll
        for (int j = 0; j < 8; j++) acc[i][j] = 0.f;

    for (int k0 = 0; k0 < 512; k0 += 32) {
        #pragma unroll
        for (int v = 0; v < 4; v++) {
            int idx = tid + v * 256;
            int r   = idx >> 3;
            int c4  = (idx & 7) << 2;
            int gm  = row0 + r;
            int rr  = gm & 4095;
            int tt  = rr >> 5, bb = rr & 31;
            const float* p;
            if (layer == 0) {
                int ts = (gm >= 4096) ? (127 - tt) : tt;  // dir1 reads reversed time
                p = src + ((size_t)bb * 128 + ts) * 512 + (k0 + c4);
            } else {
                p = src + (((size_t)(gm >> 12) * 128 + tt) * 32 + bb) * 512 + (k0 + c4);
            }
            float4 vv = *(const float4*)p;
            As[c4 + 0][r] = vv.x; As[c4 + 1][r] = vv.y;
            As[c4 + 2][r] = vv.z; As[c4 + 3][r] = vv.w;
        }
        #pragma unroll
        for (int v = 0; v < 4; v++) {
            int idx = tid + v * 256;
            int kr  = idx >> 5;
            int c4  = (idx & 31) << 2;
            *(float4*)&Ws[kr][c4] = *(const float4*)(Wbase + (size_t)(k0 + kr) * wstride + c4);
        }
        __syncthreads();
        #pragma unroll
        for (int kk = 0; kk < 32; kk++) {
            float a[8], w[8];
            *(float4*)&a[0] = *(const float4*)&As[kk][ty * 8];
            *(float4*)&a[4] = *(const float4*)&As[kk][ty * 8 + 4];
            *(float4*)&w[0] = *(const float4*)&Ws[kk][tx * 8];
            *(float4*)&w[4] = *(const float4*)&Ws[kk][tx * 8 + 4];
            #pragma unroll
            for (int i = 0; i < 8; i++)
                #pragma unroll
                for (int j = 0; j < 8; j++)
                    acc[i][j] += a[i] * w[j];
        }
        __syncthreads();
    }
    #pragma unroll
    for (int i = 0; i < 8; i++) {
        int gm = row0 + ty * 8 + i;
        __hip_bfloat16* dst = proj + (size_t)gm * 1536 + col0 + tx * 8;
        #pragma unroll
        for (int j = 0; j < 8; j++)
            dst[j] = __float2bfloat16(acc[i][j] + bias[tx * 8 + j]);
    }
}

// ---------------- weight repack: per-(ld,jb) contiguous slab ----------------
// slab[(ld*128+jb)][idx], idx = (g*4+cg)*12 + e*4 + ki ; k = g*4+ki, j = jb*4+cg
// e: 0 = Whh z-col j, 1 = Whh r-col 512+j, 2 = Whr g-col j.
// Also zeroes the dataflow slots (must run before the gru kernels).
__global__ __launch_bounds__(256)
void repack_kernel(const float* __restrict__ Whh, const float* __restrict__ Whr,
                   float* __restrict__ slabs)
{
    if (blockIdx.x == 0)
        for (int i = threadIdx.x; i < 8192; i += 256) g_slots[i] = 0u;
    const int blk = blockIdx.x;           // 0..511 = ld*128 + jb
    const int ld = blk >> 7, jb = blk & 127;
    const float* WhhL = Whh + (size_t)ld * 512 * 1024;
    const float* WhrL = Whr + (size_t)ld * 512 * 512;
    float* out = slabs + (size_t)blk * SLAB_PER_BLK;
    for (int u = 0; u < 24; u++) {
        int idx = threadIdx.x + u * 256;  // 0..6143
        int rec = idx / 12, r3 = idx % 12;
        int g = rec >> 2, cg = rec & 3;
        int e = r3 >> 2, ki = r3 & 3;
        int k = g * 4 + ki, j = jb * 4 + cg;
        float v;
        if (e == 0)      v = WhhL[(size_t)k * 1024 + j];
        else if (e == 1) v = WhhL[(size_t)k * 1024 + 512 + j];
        else             v = WhrL[(size_t)k * 512 + j];
        out[idx] = v;
    }
}

// ---------------- fused GRU sequence: barrier-free wave dataflow ----------------
// grid 256 = d*128 + jb, block 1024: thread = (cgi=tid&3, kq=(tid>>2)&7, b=tid>>5);
// wave w = tid>>6 owns rows b in {2w, 2w+1}. The dependency graph is wave-granular:
// wave w's GEMV reads h only for its 2 rows, produced by wave w of the other 127
// blocks. Per-wave poll of 128 slots (2 coalesced sc1 dwords/lane), per-wave
// staging into a PRIVATE 4KB hs region (no cross-wave LDS hazard), per-wave publish
// after a wave-local vmcnt(0) drain. ZERO __syncthreads in the t-loop.
// R10 hardening vs R9 (container failed; no identifiable deadlock cycle, but 4096
// polling waves at s_sleep(1) cadence can saturate the LLC with slot traffic and
// livelock-starve the producers' publishes): tiered backoff — 2 fast polls, then
// s_sleep(8) (~512cy) — cuts steady-state poll pressure ~8x, adds <=0.2us wakeup.
// GEMV/weights/numerics identical to R7 (same summation order -> same absmax);
// hv_self in a register (R8-proven).
__global__ __launch_bounds__(1024, 4)
void gru_seq_kernel(const __hip_bfloat16* __restrict__ proj, float* __restrict__ seq,
                    const float* __restrict__ slabs,
                    const float* __restrict__ bhh, const float* __restrict__ bhr,
                    int layer)
{
    __shared__ __align__(16) float hs[16 * 1024];  // per-wave 4KB: [w][row2][slot128*4]
    __shared__ __align__(16) float wlds[4100];     // wz/wr compact, kq>=4 half +4 floats
    const int tid  = threadIdx.x;
    const int d    = blockIdx.x >> 7;
    const int jb   = blockIdx.x & 127;
    const int ld   = layer * 2 + d;
    const int cgi  = tid & 3;
    const int kq   = (tid >> 2) & 7;
    const int b    = tid >> 5;
    const int w    = tid >> 6;
    const int lane = tid & 63;
    const int brl  = (tid >> 5) & 1;
    const int j    = jb * 4 + cgi;

    // loop invariants
    const f32x4* wrec = (const f32x4*)slabs + (size_t)(ld * 128 + jb) * 1536;
    const float bz = bhh[ld * 1024 + j];
    const float br = bhh[ld * 1024 + 512 + j];
    const float bg = bhr[ld * 512 + j];
    const float* hbase = seq + (size_t)(d * 128) * 32 * 512;
    const __hip_bfloat16* pbase = proj + ((size_t)(d * 128) * 32 + b) * 1536 + j;
    float* wout = seq + ((size_t)(d * 128) * 32 + b) * 512 + j;

    // wave-chain slot block: 128 contiguous dwords for (layer, w, d)
    unsigned* sp   = g_slots + layer * 4096 + ((w * 2 + d) << 7);
    unsigned* s0p  = sp + lane;          // coalesced per-lane poll targets
    unsigned* s1p  = sp + 64 + lane;
    unsigned* spub = sp + jb;            // this wave's own slot
    float* hw = &hs[w * 1024];           // wave-private staging region (4KB)

    // one-time: stage wz/wr into compact LDS layout (1 float4 per thread).
    {
        int i = tid;                     // 0..1023
        ((f32x4*)wlds)[i + (i >= 512 ? 1 : 0)] = wrec[(i >> 1) * 3 + (i & 1)];
    }
    __syncthreads();                     // wlds visible to all waves (only barrier)

    __hip_bfloat16 rz = pbase[0], rr_ = pbase[512], rg = pbase[1024];
    float hv_prev = 0.f;                 // h(t-1)[b][j] — this thread computes it

    for (int t = 0; t < 128; ++t) {
        float az = 0.f, ar = 0.f, ag = 0.f;
        if (t > 0) {
            // wait for this wave's 128 producers (wave w of every jb block),
            // tiered backoff to bound LLC poll pressure
            const unsigned tgt = (unsigned)t;
            int spins = 0;
            for (;;) {
                unsigned a = __hip_atomic_load(s0p, __ATOMIC_RELAXED,
                                               __HIP_MEMORY_SCOPE_AGENT);
                unsigned c = __hip_atomic_load(s1p, __ATOMIC_RELAXED,
                                               __HIP_MEMORY_SCOPE_AGENT);
                if (__all(a >= tgt && c >= tgt)) break;
                if (spins < 2) { __builtin_amdgcn_s_sleep(1); spins++; }
                else           { __builtin_amdgcn_s_sleep(8); }
            }
            asm volatile("" ::: "memory");   // keep staging loads below the poll

            // stage h(t-1)[2w..2w+1][:] (4KB, contiguous) into wave-private hs,
            // swizzle slot = g ^ ((g>>4)&7) so GEMV reads are 2-way (free)
            const float* hsrc = hbase + ((size_t)(t - 1) * 32 + 2 * w) * 512;
            f32x4 tmp[4];
            #pragma unroll
            for (int v = 0; v < 4; v++) {
                int id = lane + v * 64;          // f4 id 0..255 within wave tile
                asm volatile("global_load_dwordx4 %0, %1, off sc0 sc1"
                             : "=v"(tmp[v])
                             : "v"((const void*)(hsrc + (size_t)id * 4)));
            }
            asm volatile("s_waitcnt vmcnt(0)" ::: "memory");
            #pragma unroll
            for (int v = 0; v < 4; v++) {
                int id  = lane + v * 64;
                int row = id >> 7, g = id & 127;
                int sl  = g ^ ((g >> 4) & 7);
                *(f32x4*)&hw[row * 512 + (sl << 2)] = tmp[v];
            }
            // no barrier: hw is wave-private; compiler inserts lgkmcnt for RAW

            #pragma unroll 8
            for (int gg = 0; gg < 16; gg++) {
                int g   = kq * 16 + gg;
                int sl  = g ^ kq;                 // (g>>4)&7 == kq here
                int rec = g * 4 + cgi;
                float4 h4 = *(const float4*)&hw[brl * 512 + (sl << 2)];
                const f32x4* wp = (const f32x4*)wlds + (rec << 1) + (kq >> 2);
                f32x4 wz = wp[0], wr = wp[1];     // LDS (volume-floor reads)
                f32x4 wg = wrec[rec * 3 + 2];     // global slab, L1-resident
                az += h4.x * wz.x + h4.y * wz.y + h4.z * wz.z + h4.w * wz.w;
                ar += h4.x * wr.x + h4.y * wr.y + h4.z * wr.z + h4.w * wr.w;
                ag += h4.x * wg.x + h4.y * wg.y + h4.z * wg.z + h4.w * wg.w;
            }
            // combine the 8 k-slices (kq = lane bits 2..4)
            az += __shfl_xor(az, 4, 64);  ar += __shfl_xor(ar, 4, 64);  ag += __shfl_xor(ag, 4, 64);
            az += __shfl_xor(az, 8, 64);  ar += __shfl_xor(ar, 8, 64);  ag += __shfl_xor(ag, 8, 64);
            az += __shfl_xor(az, 16, 64); ar += __shfl_xor(ar, 16, 64); ag += __shfl_xor(ag, 16, 64);
        }

        float pz = __bfloat162float(rz);
        float pr = __bfloat162float(rr_);
        float pg = __bfloat162float(rg);
        float z  = 1.f / (1.f + __expf(-(az + pz + bz)));
        float r  = 1.f / (1.f + __expf(-(ar + pr + br)));
        float gt = tanhf((ag + bg) * r + pg);
        float hn = z * hv_prev + (1.f - z) * gt;
        hv_prev = hn;                      // becomes hv_self of step t+1
        if (kq == 0)   // coherent (sc1) write-through: LLC is the merge point
            __hip_atomic_store(wout + (size_t)t * 32 * 512, hn,
                               __ATOMIC_RELAXED, __HIP_MEMORY_SCOPE_AGENT);

        // ---- wave-local release + publish (no block barrier) ----
        if (t < 127) {
            asm volatile("s_waitcnt vmcnt(0)" ::: "memory");  // h stores LLC-ack'd
            if (lane == 0)
                __hip_atomic_store(spub, (unsigned)(t + 1),
                                   __ATOMIC_RELAXED, __HIP_MEMORY_SCOPE_AGENT);
            // prefetch next-step proj; overlaps the next wait
            const __hip_bfloat16* pn = pbase + (size_t)(t + 1) * 32 * 1536;
            rz = pn[0]; rr_ = pn[512]; rg = pn[1024];
        }
    }
}

// ---------------- final FC ----------------
__global__ __launch_bounds__(256)
void fc_kernel(const float* __restrict__ seq, const float* __restrict__ Wfc,
               const float* __restrict__ bfc, float* __restrict__ out)
{
    int idx = blockIdx.x * 256 + threadIdx.x;   // 0..16383
    int b = idx >> 9, o = idx & 511;
    const float* catf = seq + ((size_t)(0 * 128 + 127) * 32 + b) * 512;  // fwd, t=127
    const float* catr = seq + ((size_t)(1 * 128 + 0) * 32 + b) * 512;    // rev, t=0
    float acc = bfc[o];
    #pragma unroll 8
    for (int k = 0; k < 512; k++) acc += catf[k] * Wfc[(size_t)k * 512 + o];
    #pragma unroll 8
    for (int k = 0; k < 512; k++) acc += catr[k] * Wfc[(size_t)(512 + k) * 512 + o];
    out[(size_t)b * 512 + o] = acc;
}

extern "C" void kernel_launch(void* const* d_in, const int* in_sizes, int n_in,
                              void* d_out, int out_size, void* d_ws, size_t ws_size,
                              hipStream_t stream) {
    (void)in_sizes; (void)n_in; (void)out_size; (void)ws_size;
    const float* x   = (const float*)d_in[0];
    const float* Wxh = (const float*)d_in[1];
    const float* bxh = (const float*)d_in[2];
    const float* Whh = (const float*)d_in[3];
    const float* bhh = (const float*)d_in[4];
    const float* Wxr = (const float*)d_in[5];
    const float* bxr = (const float*)d_in[6];
    const float* Whr = (const float*)d_in[7];
    const float* bhr = (const float*)d_in[8];
    const float* Wfc = (const float*)d_in[9];
    const float* bfc = (const float*)d_in[10];
    float* out = (float*)d_out;

    char* base = (char*)d_ws;
    __hip_bfloat16* proj = (__hip_bfloat16*)base;
    float* seq   = (float*)(base + (size_t)PROJ_ELEMS * 2);
    float* slabs = seq + SEQ_ELEMS;

    repack_kernel<<<512, 256, 0, stream>>>(Whh, Whr, slabs);

    dim3 pgrid(12, 64);
    proj_kernel<<<pgrid, 256, 0, stream>>>(x, Wxh, bxh, Wxr, bxr, proj, 0);
    {
        int layer = 0;
        void* args[] = {(void*)&proj, (void*)&seq, (void*)&slabs,
                        (void*)&bhh, (void*)&bhr, (void*)&layer};
        hipLaunchCooperativeKernel((void*)gru_seq_kernel, dim3(256), dim3(1024),
                                   args, 0, stream);
    }
    proj_kernel<<<pgrid, 256, 0, stream>>>(seq, Wxh, bxh, Wxr, bxr, proj, 1);
    {
        int layer = 1;
        void* args[] = {(void*)&proj, (void*)&seq, (void*)&slabs,
                        (void*)&bhh, (void*)&bhr, (void*)&layer};
        hipLaunchCooperativeKernel((void*)gru_seq_kernel, dim3(256), dim3(1024),
                                   args, 0, stream);
    }
    fc_kernel<<<64, 256, 0, stream>>>(seq, Wfc, bfc, out);
}

// Round 11
// 2673.147 us; speedup vs baseline: 2.6319x; 2.6319x over previous
//
#include <hip/hip_runtime.h>
#include <hip/hip_bf16.h>

// Problem: B=32, T=128, I=H=O=512, L=2, bidirectional GRU + FC head.
// ws layout (bytes):
//   proj (bf16): [2][128][32][1536]            = 12,582,912 elems * 2B = 25.17 MB
//   seq  (fp32): [2][128][32][512]             =  4,194,304 elems * 4B = 16.78 MB
//   slabs(fp32): [2l][2d][128jb][6144]         =  6,291,456 elems * 4B = 25.17 MB
// total 67.12 MB; sync slots live in __device__ globals (zeroed by repack each launch)
#define PROJ_ELEMS 12582912
#define SEQ_ELEMS  4194304
#define SLAB_PER_BLK 6144

typedef float f32x4 __attribute__((ext_vector_type(4)));

// Block-granular dataflow slots (R7-proven): g_slots[ld*128 + jb] = epoch published
// by block (d,jb) of layer ld: value t+1 means h(t) cols [4jb,4jb+4) are LLC-visible.
// All traffic RELAXED agent-scope (sc1) — no wbl2/inv. Monotonic, no reset.
__device__ unsigned g_slots[512];

// ---------------- proj GEMM: [8192 x 1536] = src @ [Wxh | Wxr] + bias -> bf16 ----------------
// grid (12, 64), block 256. 128x128 tile, 8x8 per-thread register tile.
__global__ __launch_bounds__(256)
void proj_kernel(const float* __restrict__ src,
                 const float* __restrict__ Wxh, const float* __restrict__ bxh,
                 const float* __restrict__ Wxr, const float* __restrict__ bxr,
                 __hip_bfloat16* __restrict__ proj, int layer)
{
    __shared__ float As[32][137];   // [k][row] transposed A tile
    __shared__ float Ws[32][132];   // [k][col]
    const int tid  = threadIdx.x;
    const int col0 = blockIdx.x * 128;
    const int row0 = blockIdx.y * 128;
    const int d    = row0 >> 12;              // rows 0..4095 = dir0, 4096..8191 = dir1
    const int ld   = layer * 2 + d;
    const int tx = tid & 15, ty = tid >> 4;

    const bool is_xr = (col0 >= 1024);
    const float* Wbase = is_xr ? (Wxr + (size_t)ld * 512 * 512 + (col0 - 1024))
                               : (Wxh + (size_t)ld * 512 * 1024 + col0);
    const int wstride = is_xr ? 512 : 1024;
    const float* bias = is_xr ? (bxr + ld * 512 + (col0 - 1024))
                              : (bxh + ld * 1024 + col0);

    float acc[8][8];
    #pragma unroll
    for (int i = 0; i < 8; i++)
        #pragma unroll
        for (int j = 0; j < 8; j++) acc[i][j] = 0.f;

    for (int k0 = 0; k0 < 512; k0 += 32) {
        #pragma unroll
        for (int v = 0; v < 4; v++) {
            int idx = tid + v * 256;
            int r   = idx >> 3;
            int c4  = (idx & 7) << 2;
            int gm  = row0 + r;
            int rr  = gm & 4095;
            int tt  = rr >> 5, bb = rr & 31;
            const float* p;
            if (layer == 0) {
                int ts = (gm >= 4096) ? (127 - tt) : tt;  // dir1 reads reversed time
                p = src + ((size_t)bb * 128 + ts) * 512 + (k0 + c4);
            } else {
                p = src + (((size_t)(gm >> 12) * 128 + tt) * 32 + bb) * 512 + (k0 + c4);
            }
            float4 vv = *(const float4*)p;
            As[c4 + 0][r] = vv.x; As[c4 + 1][r] = vv.y;
            As[c4 + 2][r] = vv.z; As[c4 + 3][r] = vv.w;
        }
        #pragma unroll
        for (int v = 0; v < 4; v++) {
            int idx = tid + v * 256;
            int kr  = idx >> 5;
            int c4  = (idx & 31) << 2;
            *(float4*)&Ws[kr][c4] = *(const float4*)(Wbase + (size_t)(k0 + kr) * wstride + c4);
        }
        __syncthreads();
        #pragma unroll
        for (int kk = 0; kk < 32; kk++) {
            float a[8], w[8];
            *(float4*)&a[0] = *(const float4*)&As[kk][ty * 8];
            *(float4*)&a[4] = *(const float4*)&As[kk][ty * 8 + 4];
            *(float4*)&w[0] = *(const float4*)&Ws[kk][tx * 8];
            *(float4*)&w[4] = *(const float4*)&Ws[kk][tx * 8 + 4];
            #pragma unroll
            for (int i = 0; i < 8; i++)
                #pragma unroll
                for (int j = 0; j < 8; j++)
                    acc[i][j] += a[i] * w[j];
        }
        __syncthreads();
    }
    #pragma unroll
    for (int i = 0; i < 8; i++) {
        int gm = row0 + ty * 8 + i;
        __hip_bfloat16* dst = proj + (size_t)gm * 1536 + col0 + tx * 8;
        #pragma unroll
        for (int j = 0; j < 8; j++)
            dst[j] = __float2bfloat16(acc[i][j] + bias[tx * 8 + j]);
    }
}

// ---------------- weight repack: per-(ld,jb) contiguous slab ----------------
// slab[(ld*128+jb)][idx], idx = (g*4+cg)*12 + e*4 + ki ; k = g*4+ki, j = jb*4+cg
// e: 0 = Whh z-col j, 1 = Whh r-col 512+j, 2 = Whr g-col j.
// Also zeroes the dataflow slots (must run before the gru kernels).
__global__ __launch_bounds__(256)
void repack_kernel(const float* __restrict__ Whh, const float* __restrict__ Whr,
                   float* __restrict__ slabs)
{
    if (blockIdx.x == 0) {
        g_slots[threadIdx.x] = 0u;
        g_slots[threadIdx.x + 256] = 0u;
    }
    const int blk = blockIdx.x;           // 0..511 = ld*128 + jb
    const int ld = blk >> 7, jb = blk & 127;
    const float* WhhL = Whh + (size_t)ld * 512 * 1024;
    const float* WhrL = Whr + (size_t)ld * 512 * 512;
    float* out = slabs + (size_t)blk * SLAB_PER_BLK;
    for (int u = 0; u < 24; u++) {
        int idx = threadIdx.x + u * 256;  // 0..6143
        int rec = idx / 12, r3 = idx % 12;
        int g = rec >> 2, cg = rec & 3;
        int e = r3 >> 2, ki = r3 & 3;
        int k = g * 4 + ki, j = jb * 4 + cg;
        float v;
        if (e == 0)      v = WhhL[(size_t)k * 1024 + j];
        else if (e == 1) v = WhhL[(size_t)k * 1024 + 512 + j];
        else             v = WhrL[(size_t)k * 512 + j];
        out[idx] = v;
    }
}

// ---------------- fused GRU sequence: all 128 timesteps, one launch ----------------
// R11 = the proven R7 block-granular skeleton + only individually-proven grafts:
// (a) register hv_self (R8): each thread computes hn for its own (b,j), so step t's
//     self-h is last step's register — no LDS self-read;
// (b) wave-private staging (R10 numerics): wave w stages ONLY its rows {2w,2w+1}
//     (4KB) into a private hs region -> no cross-wave staging dependency -> the
//     post-staging __syncthreads of R7 is deleted. ONE barrier/step remains
//     (pre-publish, drains all waves' sc1 h-stores before slot[jb] is set).
// Publish/poll stays BLOCK-granular: R10 measured wave-granular chains at 2.9x
// worse (poll traffic became a first-order memory stream; every chain still waits
// on all 128 blocks, so decoupling only removed the straggler pooling).
// Thread map / GEMV / weights / summation order identical to R7 -> same absmax.
__global__ __launch_bounds__(1024, 4)
void gru_seq_kernel(const __hip_bfloat16* __restrict__ proj, float* __restrict__ seq,
                    const float* __restrict__ slabs,
                    const float* __restrict__ bhh, const float* __restrict__ bhr,
                    int layer)
{
    __shared__ __align__(16) float hs[16 * 1024];  // per-wave 4KB: [w][row2][slot128*4]
    __shared__ __align__(16) float wlds[4100];     // wz/wr compact, kq>=4 half +4 floats
    const int tid  = threadIdx.x;
    const int d    = blockIdx.x >> 7;
    const int jb   = blockIdx.x & 127;
    const int ld   = layer * 2 + d;
    const int cgi  = tid & 3;
    const int kq   = (tid >> 2) & 7;
    const int b    = tid >> 5;
    const int w    = tid >> 6;
    const int lane = tid & 63;
    const int brl  = (tid >> 5) & 1;
    const int j    = jb * 4 + cgi;

    // loop invariants
    const f32x4* wrec = (const f32x4*)slabs + (size_t)(ld * 128 + jb) * 1536;
    const float bz = bhh[ld * 1024 + j];
    const float br = bhh[ld * 1024 + 512 + j];
    const float bg = bhr[ld * 512 + j];
    const float* hbase = seq + (size_t)(d * 128) * 32 * 512;
    const __hip_bfloat16* pbase = proj + ((size_t)(d * 128) * 32 + b) * 1536 + j;
    float* wout = seq + ((size_t)(d * 128) * 32 + b) * 512 + j;
    unsigned* slot_base = &g_slots[ld * 128];
    unsigned* s0p = slot_base + lane;    // each wave polls all 128 block slots
    unsigned* s1p = s0p + 64;
    float* hw = &hs[w * 1024];           // wave-private staging region (4KB)

    // one-time: stage wz/wr into compact LDS layout (1 float4 per thread).
    {
        int i = tid;                     // 0..1023
        ((f32x4*)wlds)[i + (i >= 512 ? 1 : 0)] = wrec[(i >> 1) * 3 + (i & 1)];
    }
    __syncthreads();                     // wlds visible to all waves

    __hip_bfloat16 rz = pbase[0], rr_ = pbase[512], rg = pbase[1024];
    float hv_prev = 0.f;                 // h(t-1)[b][j] — this thread computes it

    for (int t = 0; t < 128; ++t) {
        float az = 0.f, ar = 0.f, ag = 0.f;
        if (t > 0) {
            // wait until ALL 128 producer blocks published h(t-1)  (proven R7 poll)
            const unsigned tgt = (unsigned)t;
            for (;;) {
                unsigned a = __hip_atomic_load(s0p, __ATOMIC_RELAXED,
                                               __HIP_MEMORY_SCOPE_AGENT);
                unsigned c = __hip_atomic_load(s1p, __ATOMIC_RELAXED,
                                               __HIP_MEMORY_SCOPE_AGENT);
                if (__all(a >= tgt && c >= tgt)) break;
                __builtin_amdgcn_s_sleep(1);
            }
            asm volatile("" ::: "memory");   // keep staging loads below the poll

            // stage h(t-1)[2w..2w+1][:] (4KB contiguous) into wave-private hs;
            // swizzle slot = g ^ ((g>>4)&7) -> GEMV reads are a free 2-way
            const float* hsrc = hbase + ((size_t)(t - 1) * 32 + 2 * w) * 512;
            f32x4 tmp[4];
            #pragma unroll
            for (int v = 0; v < 4; v++) {
                int id = lane + v * 64;          // f4 id 0..255 within wave tile
                asm volatile("global_load_dwordx4 %0, %1, off sc0 sc1"
                             : "=v"(tmp[v])
                             : "v"((const void*)(hsrc + (size_t)id * 4)));
            }
            asm volatile("s_waitcnt vmcnt(0)" ::: "memory");
            #pragma unroll
            for (int v = 0; v < 4; v++) {
                int id  = lane + v * 64;
                int row = id >> 7, g = id & 127;
                int sl  = g ^ ((g >> 4) & 7);
                *(f32x4*)&hw[row * 512 + (sl << 2)] = tmp[v];
            }
            // no barrier: hw is wave-private; compiler inserts lgkmcnt for RAW

            #pragma unroll 8
            for (int gg = 0; gg < 16; gg++) {
                int g   = kq * 16 + gg;
                int sl  = g ^ kq;                 // (g>>4)&7 == kq here
                int rec = g * 4 + cgi;
                float4 h4 = *(const float4*)&hw[brl * 512 + (sl << 2)];
                const f32x4* wp = (const f32x4*)wlds + (rec << 1) + (kq >> 2);
                f32x4 wz = wp[0], wr = wp[1];     // LDS (volume-floor reads)
                f32x4 wg = wrec[rec * 3 + 2];     // global slab, L1-resident
                az += h4.x * wz.x + h4.y * wz.y + h4.z * wz.z + h4.w * wz.w;
                ar += h4.x * wr.x + h4.y * wr.y + h4.z * wr.z + h4.w * wr.w;
                ag += h4.x * wg.x + h4.y * wg.y + h4.z * wg.z + h4.w * wg.w;
            }
            // combine the 8 k-slices (kq = lane bits 2..4)
            az += __shfl_xor(az, 4, 64);  ar += __shfl_xor(ar, 4, 64);  ag += __shfl_xor(ag, 4, 64);
            az += __shfl_xor(az, 8, 64);  ar += __shfl_xor(ar, 8, 64);  ag += __shfl_xor(ag, 8, 64);
            az += __shfl_xor(az, 16, 64); ar += __shfl_xor(ar, 16, 64); ag += __shfl_xor(ag, 16, 64);
        }

        float pz = __bfloat162float(rz);
        float pr = __bfloat162float(rr_);
        float pg = __bfloat162float(rg);
        float z  = 1.f / (1.f + __expf(-(az + pz + bz)));
        float r  = 1.f / (1.f + __expf(-(ar + pr + br)));
        float gt = tanhf((ag + bg) * r + pg);
        float hn = z * hv_prev + (1.f - z) * gt;
        hv_prev = hn;                      // becomes hv_self of step t+1
        if (kq == 0)   // coherent (sc1) write-through: LLC is the merge point
            __hip_atomic_store(wout + (size_t)t * 32 * 512, hn,
                               __ATOMIC_RELAXED, __HIP_MEMORY_SCOPE_AGENT);

        // ---- single per-step barrier + block-granular publish (proven R7) ----
        if (t < 127) {
            __syncthreads();   // each wave drains vmcnt(0): all sc1 h-stores visible
            if (tid == 0)      // relaxed slot store (sc1) — no wbl2
                __hip_atomic_store(slot_base + jb, (unsigned)(t + 1),
                                   __ATOMIC_RELAXED, __HIP_MEMORY_SCOPE_AGENT);
            // prefetch next-step proj; overlaps the next wait
            const __hip_bfloat16* pn = pbase + (size_t)(t + 1) * 32 * 1536;
            rz = pn[0]; rr_ = pn[512]; rg = pn[1024];
        }
    }
}

// ---------------- final FC ----------------
__global__ __launch_bounds__(256)
void fc_kernel(const float* __restrict__ seq, const float* __restrict__ Wfc,
               const float* __restrict__ bfc, float* __restrict__ out)
{
    int idx = blockIdx.x * 256 + threadIdx.x;   // 0..16383
    int b = idx >> 9, o = idx & 511;
    const float* catf = seq + ((size_t)(0 * 128 + 127) * 32 + b) * 512;  // fwd, t=127
    const float* catr = seq + ((size_t)(1 * 128 + 0) * 32 + b) * 512;    // rev, t=0
    float acc = bfc[o];
    #pragma unroll 8
    for (int k = 0; k < 512; k++) acc += catf[k] * Wfc[(size_t)k * 512 + o];
    #pragma unroll 8
    for (int k = 0; k < 512; k++) acc += catr[k] * Wfc[(size_t)(512 + k) * 512 + o];
    out[(size_t)b * 512 + o] = acc;
}

extern "C" void kernel_launch(void* const* d_in, const int* in_sizes, int n_in,
                              void* d_out, int out_size, void* d_ws, size_t ws_size,
                              hipStream_t stream) {
    (void)in_sizes; (void)n_in; (void)out_size; (void)ws_size;
    const float* x   = (const float*)d_in[0];
    const float* Wxh = (const float*)d_in[1];
    const float* bxh = (const float*)d_in[2];
    const float* Whh = (const float*)d_in[3];
    const float* bhh = (const float*)d_in[4];
    const float* Wxr = (const float*)d_in[5];
    const float* bxr = (const float*)d_in[6];
    const float* Whr = (const float*)d_in[7];
    const float* bhr = (const float*)d_in[8];
    const float* Wfc = (const float*)d_in[9];
    const float* bfc = (const float*)d_in[10];
    float* out = (float*)d_out;

    char* base = (char*)d_ws;
    __hip_bfloat16* proj = (__hip_bfloat16*)base;
    float* seq   = (float*)(base + (size_t)PROJ_ELEMS * 2);
    float* slabs = seq + SEQ_ELEMS;

    repack_kernel<<<512, 256, 0, stream>>>(Whh, Whr, slabs);

    dim3 pgrid(12, 64);
    proj_kernel<<<pgrid, 256, 0, stream>>>(x, Wxh, bxh, Wxr, bxr, proj, 0);
    {
        int layer = 0;
        void* args[] = {(void*)&proj, (void*)&seq, (void*)&slabs,
                        (void*)&bhh, (void*)&bhr, (void*)&layer};
        hipLaunchCooperativeKernel((void*)gru_seq_kernel, dim3(256), dim3(1024),
                                   args, 0, stream);
    }
    proj_kernel<<<pgrid, 256, 0, stream>>>(seq, Wxh, bxh, Wxr, bxr, proj, 1);
    {
        int layer = 1;
        void* args[] = {(void*)&proj, (void*)&seq, (void*)&slabs,
                        (void*)&bhh, (void*)&bhr, (void*)&layer};
        hipLaunchCooperativeKernel((void*)gru_seq_kernel, dim3(256), dim3(1024),
                                   args, 0, stream);
    }
    fc_kernel<<<64, 256, 0, stream>>>(seq, Wfc, bfc, out);
}